// Round 18
// baseline (50.652 us; speedup 1.0000x reference)
//
#include <hip/hip_runtime.h>

#define N_NODES 4096
#define DMODEL  256
#define NHEAD   8
#define HDIM    32
#define LN_EPS  1e-5f
#define MAXDEG  64   // padded-CSR row capacity (Poisson λ≈17, P(>64)≈0)

typedef __attribute__((ext_vector_type(8))) short short8;
typedef __attribute__((ext_vector_type(4))) float f32x4;

__device__ __forceinline__ unsigned short f2bf(float f) {
  unsigned int x = __float_as_uint(f);
  x += 0x7fffu + ((x >> 16) & 1u);   // round-to-nearest-even
  return (unsigned short)(x >> 16);
}
__device__ __forceinline__ float bf2f(unsigned short u) {
  return __uint_as_float(((unsigned int)u) << 16);
}

// --- prep: sections by blockIdx.x ---
//  [0,256)        : stage weights Wt[m][kk][kgrp][n][8j] via LDS tile
//  [256,256+EB)   : clear touched bitmap words (edge-driven)
//  [256+EB, +16)  : clear cnt[4096]
__global__ __launch_bounds__(256) void prep_kernel(
    const float* __restrict__ w0, const float* __restrict__ w1,
    const float* __restrict__ w2, const float* __restrict__ w3,
    unsigned short* __restrict__ wt,
    const int* __restrict__ e0, const int* __restrict__ e1, int ne, int eb,
    unsigned int* __restrict__ bits, int* __restrict__ cnt) {
  __shared__ float t[32][33];
  int bid = blockIdx.x, tid = threadIdx.x;
  if (bid < 256) {
    int kbi = bid & 7, nbi = (bid >> 3) & 7, m = bid >> 6;
    const float* w = (m == 0) ? w0 : (m == 1) ? w1 : (m == 2) ? w2 : w3;
    int tx = tid & 31, ty = tid >> 5;   // 32 x 8
    int kb = kbi * 32, nb = nbi * 32;
#pragma unroll
    for (int r = 0; r < 32; r += 8)
      t[ty + r][tx] = w[(kb + ty + r) * 256 + nb + tx];   // coalesced in n
    __syncthreads();
    unsigned short* o = wt + m * 65536;
    // thread (tx, ty+r) writes element (n = nb+ty+r, k = kb+tx)
#pragma unroll
    for (int r = 0; r < 32; r += 8)
      o[(kbi * 4 + (tx >> 3)) * 2048 + (nb + ty + r) * 8 + (tx & 7)] =
          f2bf(t[tx][ty + r]);
  } else if (bid < 256 + eb) {
    int i = (bid - 256) * 256 + tid;
    if (i < ne) {
      unsigned int bitpos = ((unsigned int)e0[i] << 12) | (unsigned int)e1[i];
      bits[bitpos >> 5] = 0u;
    }
  } else {
    cnt[(bid - 256 - eb) * 256 + tid] = 0;
  }
}

// ------ fused: QKV GEMM (col-split, 512 blocks x 8 waves) + edge scatter ----
// blocks [0,512): GEMM — mb = bid>>1 (16 rows), half = bid&1 (128 cols);
//                 each wave: 16 cols x 3 mats. 4096 waves = 16 waves/CU.
// blocks [512, +EB): edge dedup + padded-CSR scatter
__global__ __launch_bounds__(512) void qkv_scatter(
    const float* __restrict__ x, const unsigned short* __restrict__ wt,
    const float* __restrict__ bq, const float* __restrict__ bk,
    const float* __restrict__ bv,
    const int* __restrict__ e0, const int* __restrict__ e1, int ne,
    unsigned int* __restrict__ bits, int* __restrict__ cnt,
    int* __restrict__ colidx,
    unsigned short* __restrict__ Qb, unsigned short* __restrict__ Kb,
    unsigned short* __restrict__ Vb) {
  int bid = blockIdx.x, tid = threadIdx.x;
  if (bid >= 512) {
    int i = (bid - 512) * 512 + tid;
    if (i < ne) {
      int s = e0[i], d = e1[i];
      unsigned int bitpos = ((unsigned int)s << 12) | (unsigned int)d;
      unsigned int word = bitpos >> 5, msk = 1u << (bitpos & 31);
      unsigned int old = atomicOr(&bits[word], msk);
      if (!(old & msk)) {
        int pos = atomicAdd(&cnt[s], 1);
        if (pos < MAXDEG) colidx[s * MAXDEG + pos] = d;
      }
    }
    return;
  }
  int lane = tid & 63, w = tid >> 6;   // 8 waves
  int mb = bid >> 1, half = bid & 1;
  int Mbase = mb * 16;
  int arow = lane & 15, kgrp = lane >> 4;
  short8 a[8];
  const float* ab = x + (Mbase + arow) * 256 + kgrp * 8;
#pragma unroll
  for (int kk = 0; kk < 8; ++kk) {
    float4 v0 = *reinterpret_cast<const float4*>(ab + kk * 32);
    float4 v1 = *reinterpret_cast<const float4*>(ab + kk * 32 + 4);
    short8 tv;
    tv[0] = (short)f2bf(v0.x); tv[1] = (short)f2bf(v0.y);
    tv[2] = (short)f2bf(v0.z); tv[3] = (short)f2bf(v0.w);
    tv[4] = (short)f2bf(v1.x); tv[5] = (short)f2bf(v1.y);
    tv[6] = (short)f2bf(v1.z); tv[7] = (short)f2bf(v1.w);
    a[kk] = tv;
  }
  int col = half * 128 + w * 16 + arow;
#pragma unroll
  for (int mat = 0; mat < 3; ++mat) {
    const unsigned short* wm = wt + mat * 65536;
    const float* bias_p = (mat == 0) ? bq : (mat == 1) ? bk : bv;
    unsigned short* o = (mat == 0) ? Qb : (mat == 1) ? Kb : Vb;
    const unsigned short* bb = wm + kgrp * 2048 + col * 8;
    f32x4 acc = {0.f, 0.f, 0.f, 0.f};
#pragma unroll
    for (int kk = 0; kk < 8; ++kk) {
      short8 b = *reinterpret_cast<const short8*>(bb + kk * 8192);
      acc = __builtin_amdgcn_mfma_f32_16x16x32_bf16(a[kk], b, acc, 0, 0, 0);
    }
    float bias = bias_p[col];
#pragma unroll
    for (int r = 0; r < 4; ++r) {
      int row = Mbase + kgrp * 4 + r;
      o[row * 256 + col] = f2bf(acc[r] + bias);
    }
  }
}

// ----- fused attention + output GEMM + residual + LayerNorm -----------------
__global__ __launch_bounds__(1024, 1) void attn_out_ln(
    const unsigned short* __restrict__ Qb, const unsigned short* __restrict__ Kb,
    const unsigned short* __restrict__ Vb, const int* __restrict__ cnt,
    const int* __restrict__ colidx, const unsigned short* __restrict__ wot,
    const float* __restrict__ bo, const float* __restrict__ x,
    const float* __restrict__ gamma, const float* __restrict__ beta,
    float* __restrict__ out) {
  __shared__ unsigned short att_lds[16][264];  // bf16, 528B row (16B-aligned)
  __shared__ float ylds[16][260];
  __shared__ float ps[16][65], pq[16][65];
  __shared__ float mu_s[16], ri_s[16];

  int tid = threadIdx.x;
  int Mbase = blockIdx.x * 16;
  const float scale = 0.17677669529663687f;  // 1/sqrt(32)

  // ---------- attention phase: 8 lanes per (node, head) ----------
  {
    int g = tid >> 3;            // 128 groups = 16 nodes x 8 heads
    int gl = tid & 7;            // lane in group
    int ni = g >> 3, h = g & 7;
    int n = Mbase + ni;

    float qf[32];
    {
      const short8* q8 = reinterpret_cast<const short8*>(Qb + n * 256 + h * 32);
#pragma unroll
      for (int b = 0; b < 4; ++b) {
        short8 qv = q8[b];
#pragma unroll
        for (int j = 0; j < 8; ++j) qf[b * 8 + j] = bf2f((unsigned short)qv[j]) * scale;
      }
    }

    int deg = cnt[n]; deg = (deg > MAXDEG) ? MAXDEG : deg;
    const int* nbrs = colidx + n * MAXDEG;

    float s[8]; int c[8];
#pragma unroll
    for (int i = 0; i < 8; ++i) { s[i] = -3.0e38f; c[i] = 0; }
#pragma unroll
    for (int i = 0; i < 8; ++i) {
      if (8 * i >= deg) break;
      int idx = 8 * i + gl;
      if (idx < deg) {
        c[i] = nbrs[idx];
        const short8* k8 = reinterpret_cast<const short8*>(Kb + c[i] * 256 + h * 32);
        float d = 0.f;
#pragma unroll
        for (int b = 0; b < 4; ++b) {
          short8 kv = k8[b];
#pragma unroll
          for (int j = 0; j < 8; ++j)
            d += qf[b * 8 + j] * bf2f((unsigned short)kv[j]);
        }
        s[i] = d;
      }
    }

    float gm = s[0];
#pragma unroll
    for (int i = 1; i < 8; ++i) gm = fmaxf(gm, s[i]);
    gm = fmaxf(gm, __shfl_xor(gm, 1, 8));
    gm = fmaxf(gm, __shfl_xor(gm, 2, 8));
    gm = fmaxf(gm, __shfl_xor(gm, 4, 8));

    float l = 0.f;
#pragma unroll
    for (int i = 0; i < 8; ++i) {
      if (8 * i >= deg) break;
      s[i] = __expf(s[i] - gm);
      l += s[i];
    }
    l += __shfl_xor(l, 1, 8);
    l += __shfl_xor(l, 2, 8);
    l += __shfl_xor(l, 4, 8);

    float a0 = 0.f, a1 = 0.f, a2 = 0.f, a3 = 0.f;
#pragma unroll
    for (int i = 0; i < 8; ++i) {
      if (8 * i >= deg) break;
#pragma unroll
      for (int lj = 0; lj < 8; ++lj) {
        if (8 * i + lj >= deg) break;
        float pj = __shfl(s[i], lj, 8);
        int cj = __shfl(c[i], lj, 8);
        ushort4 vv = *reinterpret_cast<const ushort4*>(Vb + cj * 256 + h * 32 + gl * 4);
        a0 += pj * bf2f(vv.x);
        a1 += pj * bf2f(vv.y);
        a2 += pj * bf2f(vv.z);
        a3 += pj * bf2f(vv.w);
      }
    }
    float rl = 1.f / l;
    ushort4 pkt;
    pkt.x = f2bf(a0 * rl); pkt.y = f2bf(a1 * rl);
    pkt.z = f2bf(a2 * rl); pkt.w = f2bf(a3 * rl);
    *reinterpret_cast<ushort4*>(&att_lds[ni][h * 32 + gl * 4]) = pkt;
  }
  __syncthreads();

  // ---------- output GEMM (16 waves x 16 cols) ----------
  {
    int lane = tid & 63, w = tid >> 6;   // 16 waves
    int arow = lane & 15, kgrp = lane >> 4;

    short8 a[8];
#pragma unroll
    for (int kk = 0; kk < 8; ++kk)
      a[kk] = *reinterpret_cast<const short8*>(&att_lds[arow][kgrp * 8 + kk * 32]);

    int col = w * 16 + arow;
    const unsigned short* bb = wot + kgrp * 2048 + col * 8;
    f32x4 acc = {0.f, 0.f, 0.f, 0.f};
#pragma unroll
    for (int kk = 0; kk < 8; ++kk) {
      short8 b = *reinterpret_cast<const short8*>(bb + kk * 8192);
      acc = __builtin_amdgcn_mfma_f32_16x16x32_bf16(a[kk], b, acc, 0, 0, 0);
    }
    float bof = bo[col];
#pragma unroll
    for (int r = 0; r < 4; ++r) {
      int row = kgrp * 4 + r;
      float xv = x[(Mbase + row) * 256 + col];
      ylds[row][col] = acc[r] + bof + xv;
    }
  }
  __syncthreads();

  // ---------- LayerNorm (1024 threads: 16 rows x 64 segs of 4) ----------
  int r = tid >> 6, seg = tid & 63;
  float sm = 0.f, sq = 0.f;
#pragma unroll
  for (int j = 0; j < 4; ++j) {
    float v = ylds[r][seg * 4 + j];
    sm += v;
    sq += v * v;
  }
  ps[r][seg] = sm;
  pq[r][seg] = sq;
  __syncthreads();
  if (tid < 16) {
    float S = 0.f, Q2 = 0.f;
#pragma unroll
    for (int cc = 0; cc < 64; ++cc) { S += ps[tid][cc]; Q2 += pq[tid][cc]; }
    float mu = S * (1.f / 256.f);
    float var = Q2 * (1.f / 256.f) - mu * mu;
    mu_s[tid] = mu;
    ri_s[tid] = rsqrtf(var + LN_EPS);
  }
  __syncthreads();
  float mu = mu_s[r], ri = ri_s[r];
  float* orow = out + (Mbase + r) * 256;
#pragma unroll
  for (int j = 0; j < 4; ++j) {
    int cc = seg * 4 + j;
    float v = (ylds[r][cc] - mu) * ri * gamma[cc] + beta[cc];
    orow[cc] = v;
  }
}

// ---------------------------------------------------------------------------
extern "C" void kernel_launch(void* const* d_in, const int* in_sizes, int n_in,
                              void* d_out, int out_size, void* d_ws, size_t ws_size,
                              hipStream_t stream) {
  const float* x     = (const float*)d_in[0];
  const int*   edges = (const int*)d_in[1];
  const float* Wq    = (const float*)d_in[2];
  const float* bq    = (const float*)d_in[3];
  const float* Wk    = (const float*)d_in[4];
  const float* bk    = (const float*)d_in[5];
  const float* Wv    = (const float*)d_in[6];
  const float* bv    = (const float*)d_in[7];
  const float* Wo    = (const float*)d_in[8];
  const float* bo    = (const float*)d_in[9];
  const float* gamma = (const float*)d_in[10];
  const float* beta  = (const float*)d_in[11];
  float* out = (float*)d_out;
  int NE = in_sizes[1] / 2;
  int EB256 = (NE + 255) / 256;
  int EB512 = (NE + 511) / 512;

  // workspace carve (256B aligned)
  char* p = (char*)d_ws;
  auto carve = [&](size_t sz) { char* r = p; p += ((sz + 255) / 256) * 256; return r; };
  unsigned short* Wt   = (unsigned short*)carve(4 * 65536 * sizeof(unsigned short));
  unsigned short* Qb   = (unsigned short*)carve((size_t)N_NODES * DMODEL * sizeof(unsigned short));
  unsigned short* Kb   = (unsigned short*)carve((size_t)N_NODES * DMODEL * sizeof(unsigned short));
  unsigned short* Vb   = (unsigned short*)carve((size_t)N_NODES * DMODEL * sizeof(unsigned short));
  unsigned int*   bits = (unsigned int*)carve((size_t)N_NODES * N_NODES / 8);
  int*            cnt  = (int*)carve(N_NODES * sizeof(int));
  int*            colidx = (int*)carve((size_t)N_NODES * MAXDEG * sizeof(int));

  prep_kernel<<<256 + EB256 + 16, 256, 0, stream>>>(Wq, Wk, Wv, Wo, Wt,
                                                    edges, edges + NE, NE, EB256, bits, cnt);
  qkv_scatter<<<512 + EB512, 512, 0, stream>>>(x, Wt, bq, bk, bv,
                                               edges, edges + NE, NE, bits, cnt, colidx,
                                               Qb, Kb, Vb);
  attn_out_ln<<<256, 1024, 0, stream>>>(Qb, Kb, Vb, cnt, colidx, Wt + 3 * 65536,
                                        bo, x, gamma, beta, out);
}

// Round 19
// 48.729 us; speedup vs baseline: 1.0395x; 1.0395x over previous
//
#include <hip/hip_runtime.h>

#define N_NODES 4096
#define DMODEL  256
#define NHEAD   8
#define HDIM    32
#define LN_EPS  1e-5f
#define MAXDEG  64   // padded-CSR row capacity (Poisson λ≈17, P(>64)≈0)

typedef __attribute__((ext_vector_type(8))) short short8;
typedef __attribute__((ext_vector_type(4))) float f32x4;

__device__ __forceinline__ unsigned short f2bf(float f) {
  unsigned int x = __float_as_uint(f);
  x += 0x7fffu + ((x >> 16) & 1u);   // round-to-nearest-even
  return (unsigned short)(x >> 16);
}
__device__ __forceinline__ float bf2f(unsigned short u) {
  return __uint_as_float(((unsigned int)u) << 16);
}

// --- prep: sections by blockIdx.x ---
//  [0,256)        : stage weights Wt[m][kk][kgrp][n][8j] via LDS tile
//  [256,256+EB)   : clear touched bitmap words (edge-driven)
//  [256+EB, +16)  : clear cnt[4096]
__global__ __launch_bounds__(256) void prep_kernel(
    const float* __restrict__ w0, const float* __restrict__ w1,
    const float* __restrict__ w2, const float* __restrict__ w3,
    unsigned short* __restrict__ wt,
    const int* __restrict__ e0, const int* __restrict__ e1, int ne, int eb,
    unsigned int* __restrict__ bits, int* __restrict__ cnt) {
  __shared__ float t[32][33];
  int bid = blockIdx.x, tid = threadIdx.x;
  if (bid < 256) {
    int kbi = bid & 7, nbi = (bid >> 3) & 7, m = bid >> 6;
    const float* w = (m == 0) ? w0 : (m == 1) ? w1 : (m == 2) ? w2 : w3;
    int tx = tid & 31, ty = tid >> 5;   // 32 x 8
    int kb = kbi * 32, nb = nbi * 32;
#pragma unroll
    for (int r = 0; r < 32; r += 8)
      t[ty + r][tx] = w[(kb + ty + r) * 256 + nb + tx];   // coalesced in n
    __syncthreads();
    unsigned short* o = wt + m * 65536;
    // thread (tx, ty+r) writes element (n = nb+ty+r, k = kb+tx)
#pragma unroll
    for (int r = 0; r < 32; r += 8)
      o[(kbi * 4 + (tx >> 3)) * 2048 + (nb + ty + r) * 8 + (tx & 7)] =
          f2bf(t[tx][ty + r]);
  } else if (bid < 256 + eb) {
    int i = (bid - 256) * 256 + tid;
    if (i < ne) {
      unsigned int bitpos = ((unsigned int)e0[i] << 12) | (unsigned int)e1[i];
      bits[bitpos >> 5] = 0u;
    }
  } else {
    cnt[(bid - 256 - eb) * 256 + tid] = 0;
  }
}

// ------ fused: QKV GEMM (shared-A, 512 thr, 8 waves) + edge scatter ---------
__global__ __launch_bounds__(512) void qkv_scatter(
    const float* __restrict__ x, const unsigned short* __restrict__ wt,
    const float* __restrict__ bq, const float* __restrict__ bk,
    const float* __restrict__ bv,
    const int* __restrict__ e0, const int* __restrict__ e1, int ne,
    unsigned int* __restrict__ bits, int* __restrict__ cnt,
    int* __restrict__ colidx,
    unsigned short* __restrict__ Qb, unsigned short* __restrict__ Kb,
    unsigned short* __restrict__ Vb) {
  int bid = blockIdx.x, tid = threadIdx.x;
  if (bid >= 256) {
    int i = (bid - 256) * 512 + tid;
    if (i < ne) {
      int s = e0[i], d = e1[i];
      unsigned int bitpos = ((unsigned int)s << 12) | (unsigned int)d;
      unsigned int word = bitpos >> 5, msk = 1u << (bitpos & 31);
      unsigned int old = atomicOr(&bits[word], msk);
      if (!(old & msk)) {
        int pos = atomicAdd(&cnt[s], 1);
        if (pos < MAXDEG) colidx[s * MAXDEG + pos] = d;
      }
    }
    return;
  }
  int lane = tid & 63, w = tid >> 6;   // 8 waves
  int Mbase = bid * 16;
  int arow = lane & 15, kgrp = lane >> 4;
  short8 a[8];
  const float* ab = x + (Mbase + arow) * 256 + kgrp * 8;
#pragma unroll
  for (int kk = 0; kk < 8; ++kk) {
    float4 v0 = *reinterpret_cast<const float4*>(ab + kk * 32);
    float4 v1 = *reinterpret_cast<const float4*>(ab + kk * 32 + 4);
    short8 tv;
    tv[0] = (short)f2bf(v0.x); tv[1] = (short)f2bf(v0.y);
    tv[2] = (short)f2bf(v0.z); tv[3] = (short)f2bf(v0.w);
    tv[4] = (short)f2bf(v1.x); tv[5] = (short)f2bf(v1.y);
    tv[6] = (short)f2bf(v1.z); tv[7] = (short)f2bf(v1.w);
    a[kk] = tv;
  }
#pragma unroll
  for (int mat = 0; mat < 3; ++mat) {
    const unsigned short* wm = wt + mat * 65536;
    const float* bias_p = (mat == 0) ? bq : (mat == 1) ? bk : bv;
    unsigned short* o = (mat == 0) ? Qb : (mat == 1) ? Kb : Vb;
#pragma unroll
    for (int nf = 0; nf < 2; ++nf) {
      int col = w * 32 + nf * 16 + arow;
      const unsigned short* bb = wm + kgrp * 2048 + col * 8;
      f32x4 acc = {0.f, 0.f, 0.f, 0.f};
#pragma unroll
      for (int kk = 0; kk < 8; ++kk) {
        short8 b = *reinterpret_cast<const short8*>(bb + kk * 8192);
        acc = __builtin_amdgcn_mfma_f32_16x16x32_bf16(a[kk], b, acc, 0, 0, 0);
      }
      float bias = bias_p[col];
#pragma unroll
      for (int r = 0; r < 4; ++r) {
        int row = Mbase + kgrp * 4 + r;
        o[row * 256 + col] = f2bf(acc[r] + bias);
      }
    }
  }
}

// ----- fused attention + output GEMM + residual + LayerNorm -----------------
__global__ __launch_bounds__(1024, 1) void attn_out_ln(
    const unsigned short* __restrict__ Qb, const unsigned short* __restrict__ Kb,
    const unsigned short* __restrict__ Vb, const int* __restrict__ cnt,
    const int* __restrict__ colidx, const unsigned short* __restrict__ wot,
    const float* __restrict__ bo, const float* __restrict__ x,
    const float* __restrict__ gamma, const float* __restrict__ beta,
    float* __restrict__ out) {
  __shared__ unsigned short att_lds[16][264];  // bf16, 528B row (16B-aligned)
  __shared__ float ylds[16][260];
  __shared__ float ps[16][65], pq[16][65];
  __shared__ float mu_s[16], ri_s[16];

  int tid = threadIdx.x;
  int Mbase = blockIdx.x * 16;
  const float scale = 0.17677669529663687f;  // 1/sqrt(32)

  // ---------- attention phase: 8 lanes per (node, head) ----------
  {
    int g = tid >> 3;            // 128 groups = 16 nodes x 8 heads
    int gl = tid & 7;            // lane in group
    int ni = g >> 3, h = g & 7;
    int n = Mbase + ni;

    float qf[32];
    {
      const short8* q8 = reinterpret_cast<const short8*>(Qb + n * 256 + h * 32);
#pragma unroll
      for (int b = 0; b < 4; ++b) {
        short8 qv = q8[b];
#pragma unroll
        for (int j = 0; j < 8; ++j) qf[b * 8 + j] = bf2f((unsigned short)qv[j]) * scale;
      }
    }

    int deg = cnt[n]; deg = (deg > MAXDEG) ? MAXDEG : deg;
    const int* nbrs = colidx + n * MAXDEG;

    float s[8]; int c[8];
#pragma unroll
    for (int i = 0; i < 8; ++i) { s[i] = -3.0e38f; c[i] = 0; }
#pragma unroll
    for (int i = 0; i < 8; ++i) {
      if (8 * i >= deg) break;
      int idx = 8 * i + gl;
      if (idx < deg) {
        c[i] = nbrs[idx];
        const short8* k8 = reinterpret_cast<const short8*>(Kb + c[i] * 256 + h * 32);
        float d = 0.f;
#pragma unroll
        for (int b = 0; b < 4; ++b) {
          short8 kv = k8[b];
#pragma unroll
          for (int j = 0; j < 8; ++j)
            d += qf[b * 8 + j] * bf2f((unsigned short)kv[j]);
        }
        s[i] = d;
      }
    }

    float gm = s[0];
#pragma unroll
    for (int i = 1; i < 8; ++i) gm = fmaxf(gm, s[i]);
    gm = fmaxf(gm, __shfl_xor(gm, 1, 8));
    gm = fmaxf(gm, __shfl_xor(gm, 2, 8));
    gm = fmaxf(gm, __shfl_xor(gm, 4, 8));

    float l = 0.f;
#pragma unroll
    for (int i = 0; i < 8; ++i) {
      if (8 * i >= deg) break;
      s[i] = __expf(s[i] - gm);
      l += s[i];
    }
    l += __shfl_xor(l, 1, 8);
    l += __shfl_xor(l, 2, 8);
    l += __shfl_xor(l, 4, 8);

    float a0 = 0.f, a1 = 0.f, a2 = 0.f, a3 = 0.f;
#pragma unroll
    for (int i = 0; i < 8; ++i) {
      if (8 * i >= deg) break;
#pragma unroll
      for (int lj = 0; lj < 8; ++lj) {
        if (8 * i + lj >= deg) break;
        float pj = __shfl(s[i], lj, 8);
        int cj = __shfl(c[i], lj, 8);
        ushort4 vv = *reinterpret_cast<const ushort4*>(Vb + cj * 256 + h * 32 + gl * 4);
        a0 += pj * bf2f(vv.x);
        a1 += pj * bf2f(vv.y);
        a2 += pj * bf2f(vv.z);
        a3 += pj * bf2f(vv.w);
      }
    }
    float rl = 1.f / l;
    ushort4 pkt;
    pkt.x = f2bf(a0 * rl); pkt.y = f2bf(a1 * rl);
    pkt.z = f2bf(a2 * rl); pkt.w = f2bf(a3 * rl);
    *reinterpret_cast<ushort4*>(&att_lds[ni][h * 32 + gl * 4]) = pkt;
  }
  __syncthreads();

  // ---------- output GEMM (16 waves x 16 cols) ----------
  {
    int lane = tid & 63, w = tid >> 6;   // 16 waves
    int arow = lane & 15, kgrp = lane >> 4;

    short8 a[8];
#pragma unroll
    for (int kk = 0; kk < 8; ++kk)
      a[kk] = *reinterpret_cast<const short8*>(&att_lds[arow][kgrp * 8 + kk * 32]);

    int col = w * 16 + arow;
    const unsigned short* bb = wot + kgrp * 2048 + col * 8;
    f32x4 acc = {0.f, 0.f, 0.f, 0.f};
#pragma unroll
    for (int kk = 0; kk < 8; ++kk) {
      short8 b = *reinterpret_cast<const short8*>(bb + kk * 8192);
      acc = __builtin_amdgcn_mfma_f32_16x16x32_bf16(a[kk], b, acc, 0, 0, 0);
    }
    float bof = bo[col];
#pragma unroll
    for (int r = 0; r < 4; ++r) {
      int row = kgrp * 4 + r;
      float xv = x[(Mbase + row) * 256 + col];
      ylds[row][col] = acc[r] + bof + xv;
    }
  }
  __syncthreads();

  // ---------- LayerNorm (1024 threads: 16 rows x 64 segs of 4) ----------
  int r = tid >> 6, seg = tid & 63;
  float sm = 0.f, sq = 0.f;
#pragma unroll
  for (int j = 0; j < 4; ++j) {
    float v = ylds[r][seg * 4 + j];
    sm += v;
    sq += v * v;
  }
  ps[r][seg] = sm;
  pq[r][seg] = sq;
  __syncthreads();
  if (tid < 16) {
    float S = 0.f, Q2 = 0.f;
#pragma unroll
    for (int cc = 0; cc < 64; ++cc) { S += ps[tid][cc]; Q2 += pq[tid][cc]; }
    float mu = S * (1.f / 256.f);
    float var = Q2 * (1.f / 256.f) - mu * mu;
    mu_s[tid] = mu;
    ri_s[tid] = rsqrtf(var + LN_EPS);
  }
  __syncthreads();
  float mu = mu_s[r], ri = ri_s[r];
  float* orow = out + (Mbase + r) * 256;
#pragma unroll
  for (int j = 0; j < 4; ++j) {
    int cc = seg * 4 + j;
    float v = (ylds[r][cc] - mu) * ri * gamma[cc] + beta[cc];
    orow[cc] = v;
  }
}

// ---------------------------------------------------------------------------
extern "C" void kernel_launch(void* const* d_in, const int* in_sizes, int n_in,
                              void* d_out, int out_size, void* d_ws, size_t ws_size,
                              hipStream_t stream) {
  const float* x     = (const float*)d_in[0];
  const int*   edges = (const int*)d_in[1];
  const float* Wq    = (const float*)d_in[2];
  const float* bq    = (const float*)d_in[3];
  const float* Wk    = (const float*)d_in[4];
  const float* bk    = (const float*)d_in[5];
  const float* Wv    = (const float*)d_in[6];
  const float* bv    = (const float*)d_in[7];
  const float* Wo    = (const float*)d_in[8];
  const float* bo    = (const float*)d_in[9];
  const float* gamma = (const float*)d_in[10];
  const float* beta  = (const float*)d_in[11];
  float* out = (float*)d_out;
  int NE = in_sizes[1] / 2;
  int EB256 = (NE + 255) / 256;
  int EB512 = (NE + 511) / 512;

  // workspace carve (256B aligned)
  char* p = (char*)d_ws;
  auto carve = [&](size_t sz) { char* r = p; p += ((sz + 255) / 256) * 256; return r; };
  unsigned short* Wt   = (unsigned short*)carve(4 * 65536 * sizeof(unsigned short));
  unsigned short* Qb   = (unsigned short*)carve((size_t)N_NODES * DMODEL * sizeof(unsigned short));
  unsigned short* Kb   = (unsigned short*)carve((size_t)N_NODES * DMODEL * sizeof(unsigned short));
  unsigned short* Vb   = (unsigned short*)carve((size_t)N_NODES * DMODEL * sizeof(unsigned short));
  unsigned int*   bits = (unsigned int*)carve((size_t)N_NODES * N_NODES / 8);
  int*            cnt  = (int*)carve(N_NODES * sizeof(int));
  int*            colidx = (int*)carve((size_t)N_NODES * MAXDEG * sizeof(int));

  prep_kernel<<<256 + EB256 + 16, 256, 0, stream>>>(Wq, Wk, Wv, Wo, Wt,
                                                    edges, edges + NE, NE, EB256, bits, cnt);
  qkv_scatter<<<256 + EB512, 512, 0, stream>>>(x, Wt, bq, bk, bv,
                                               edges, edges + NE, NE, bits, cnt, colidx,
                                               Qb, Kb, Vb);
  attn_out_ln<<<256, 1024, 0, stream>>>(Qb, Kb, Vb, cnt, colidx, Wt + 3 * 65536,
                                        bo, x, gamma, beta, out);
}